// Round 10
// baseline (440.184 us; speedup 1.0000x reference)
//
#include <hip/hip_runtime.h>
#include <math.h>

namespace {

constexpr int N = 50000;
constexpr int E = 400000;
constexpr int G = 64;
constexpr int HID = 64;
constexpr int HH = 256; // NHEAD*HID
constexpr int NCT = 32; // 512 output cols (xl|xr) / 16
constexpr float NEG = 0.2f;
constexpr int GAT_BLOCKS = 2048; // 8 blocks/CU * 256 CU
constexpr int GAT_WAVES = GAT_BLOCKS * 4;

constexpr int NPROJ = (N + 31) / 32;       // 1563
constexpr int PH1 = 782;                   // proj-L0 first-half blocks (rows 0..25023)
constexpr int PH1_ROWS = PH1 * 32;         // 25024
constexpr int PH2 = NPROJ - PH1;           // 781
constexpr int HIST_BLOCKS = (E + 255) / 256; // 1563
constexpr int PACK_BLOCKS = 52;            // 13312 threads for weight pack
constexpr int ZERO_ELEMS = G * HID + N;    // pooled + deg (adjacent)
constexpr int ZERO_BLOCKS = (ZERO_ELEMS + 255) / 256; // 212

typedef __attribute__((ext_vector_type(8))) short short8v;
typedef __attribute__((ext_vector_type(4))) float f32x4;

__device__ __forceinline__ unsigned short f2bf(float f) {
    unsigned int u = __float_as_uint(f);
    u += 0x7FFFu + ((u >> 16) & 1u); // RTNE
    return (unsigned short)(u >> 16);
}
__device__ __forceinline__ float bf2f(unsigned short h) {
    return __uint_as_float(((unsigned int)h) << 16);
}
// load 4 consecutive bf16 (8B aligned) -> float4
__device__ __forceinline__ float4 ld_bf4(const unsigned short* p) {
    uint2 u = *(const uint2*)p;
    float4 r;
    r.x = __uint_as_float(u.x << 16);
    r.y = __uint_as_float(u.x & 0xFFFF0000u);
    r.z = __uint_as_float(u.y << 16);
    r.w = __uint_as_float(u.y & 0xFFFF0000u);
    return r;
}

// ---- prep: pack W (Wl|Wr as 512 cols) into MFMA B-fragment order (hi/lo bf16)
//      + zero pooled/deg (replaces the hipMemsetAsync dispatch) ----
__global__ __launch_bounds__(256) void prep_k(
    const float* __restrict__ Wl0, const float* __restrict__ Wr0,
    const float* __restrict__ bl0, const float* __restrict__ br0,
    const float* __restrict__ Wl1, const float* __restrict__ Wr1,
    const float* __restrict__ bl1, const float* __restrict__ br1,
    unsigned short* __restrict__ w0hi, unsigned short* __restrict__ w0lo,
    unsigned short* __restrict__ w1hi, unsigned short* __restrict__ w1lo,
    float* __restrict__ bc0, float* __restrict__ bc1,
    int* __restrict__ zero_base)
{
    int b = blockIdx.x;
    if (b >= PACK_BLOCKS) {
        int i = (b - PACK_BLOCKS) * 256 + threadIdx.x;
        if (i < ZERO_ELEMS) zero_base[i] = 0;
        return;
    }
    int idx = b * 256 + threadIdx.x;
    if (idx < 8192) { // layer0: KT=4, 4*32*64 slots
        int lane = idx & 63, ct = (idx >> 6) & 31, kt = idx >> 11;
        int col = ct * 16 + (lane & 15);
        const float* W = (col < 256) ? Wl0 : Wr0;
        int c = col & 255;
        int kb = kt * 32 + ((lane >> 4) & 3) * 8;
#pragma unroll
        for (int e = 0; e < 8; e++) {
            float v = W[(size_t)(kb + e) * 256 + c];
            unsigned short hi = f2bf(v);
            unsigned short lo = f2bf(v - bf2f(hi));
            w0hi[(size_t)idx * 8 + e] = hi;
            w0lo[(size_t)idx * 8 + e] = lo;
        }
    } else if (idx < 8192 + 4096) { // layer1: KT=2
        int s = idx - 8192;
        int lane = s & 63, ct = (s >> 6) & 31, kt = s >> 11;
        int col = ct * 16 + (lane & 15);
        const float* W = (col < 256) ? Wl1 : Wr1;
        int c = col & 255;
        int kb = kt * 32 + ((lane >> 4) & 3) * 8;
#pragma unroll
        for (int e = 0; e < 8; e++) {
            float v = W[(size_t)(kb + e) * 256 + c];
            unsigned short hi = f2bf(v);
            unsigned short lo = f2bf(v - bf2f(hi));
            w1hi[(size_t)s * 8 + e] = hi;
            w1lo[(size_t)s * 8 + e] = lo;
        }
    } else if (idx < 8192 + 4096 + 512) {
        int i = idx - (8192 + 4096);
        bc0[i] = (i < 256) ? bl0[i] : br0[i - 256];
    } else if (idx < 8192 + 4096 + 1024) {
        int i = idx - (8192 + 4096 + 512);
        bc1[i] = (i < 256) ? bl1[i] : br1[i - 256];
    }
}

// ---- node projection body (round-7 verified form), parameterized by row base ----
// 32 nodes x 512 cols per block. 4 waves; wave w: both 16-row tiles, col-tiles [8w,8w+8).
// Epilogue: stage bf16 tile in LDS (2 passes of 16 rows), store coalesced uint4.
template <int IC>
__device__ __forceinline__ void proj_body(
    int base,
    const float* __restrict__ x,
    const unsigned short* __restrict__ whi, const unsigned short* __restrict__ wlo,
    const float* __restrict__ bc,
    unsigned short* __restrict__ xlb, unsigned short* __restrict__ xrb)
{
    constexpr int KT = IC / 32;
    constexpr int LDX = IC + 4;     // pad: row stride stays 16B-aligned, banks spread
    constexpr int SROW = 516;       // bf16 stage row stride (1032B)
    constexpr int XS_BYTES = 32 * LDX * 4;
    constexpr int ST_BYTES = 16 * SROW * 2;
    constexpr int SMEM_BYTES = (XS_BYTES > ST_BYTES) ? XS_BYTES : ST_BYTES;
    __shared__ char smem[SMEM_BYTES];
    float (*xs)[LDX] = (float (*)[LDX])smem;
    const int tid = threadIdx.x;
    for (int idx = tid; idx < 32 * IC / 4; idx += 256) {
        int j = idx / (IC / 4), k4 = idx - j * (IC / 4);
        int n = base + j;
        float4 v = make_float4(0.f, 0.f, 0.f, 0.f);
        if (n < N) v = *(const float4*)&x[(size_t)n * IC + k4 * 4];
        *(float4*)&xs[j][k4 * 4] = v;
    }
    __syncthreads();
    const int w = tid >> 6, lane = tid & 63;
    const int lr = lane & 15, lg = lane >> 4;
    f32x4 acc[2][8];
#pragma unroll
    for (int rt = 0; rt < 2; rt++)
#pragma unroll
        for (int ct = 0; ct < 8; ct++) {
            f32x4 z = {0.f, 0.f, 0.f, 0.f};
            acc[rt][ct] = z;
        }
#pragma unroll
    for (int kt = 0; kt < KT; kt++) {
        short8v ahi[2], alo[2];
#pragma unroll
        for (int rt = 0; rt < 2; rt++) {
            const float* p = &xs[rt * 16 + lr][kt * 32 + lg * 8];
            float4 v0 = *(const float4*)p;
            float4 v1 = *(const float4*)(p + 4);
            float fv[8] = {v0.x, v0.y, v0.z, v0.w, v1.x, v1.y, v1.z, v1.w};
            short8v h, l;
#pragma unroll
            for (int e = 0; e < 8; e++) {
                unsigned short hb = f2bf(fv[e]);
                h[e] = (short)hb;
                l[e] = (short)f2bf(fv[e] - bf2f(hb));
            }
            ahi[rt] = h;
            alo[rt] = l;
        }
        const size_t bbase = ((size_t)(kt * NCT + w * 8) * 64 + lane) * 8;
#pragma unroll
        for (int ct = 0; ct < 8; ct++) {
            short8v bhi = *(const short8v*)&whi[bbase + (size_t)ct * 64 * 8];
            short8v blo = *(const short8v*)&wlo[bbase + (size_t)ct * 64 * 8];
#pragma unroll
            for (int rt = 0; rt < 2; rt++) {
                acc[rt][ct] = __builtin_amdgcn_mfma_f32_16x16x32_bf16(ahi[rt], bhi, acc[rt][ct], 0, 0, 0);
                acc[rt][ct] = __builtin_amdgcn_mfma_f32_16x16x32_bf16(alo[rt], bhi, acc[rt][ct], 0, 0, 0);
                acc[rt][ct] = __builtin_amdgcn_mfma_f32_16x16x32_bf16(ahi[rt], blo, acc[rt][ct], 0, 0, 0);
            }
        }
    }
    // epilogue: C/D layout (measured): col = lane&15, row = (lane>>4)*4 + reg
    __syncthreads(); // xs consumed into acc; reuse smem as bf16 stage
    unsigned short* st = (unsigned short*)smem;
#pragma unroll
    for (int rt = 0; rt < 2; rt++) {
#pragma unroll
        for (int ct = 0; ct < 8; ct++) {
            int col = (w * 8 + ct) * 16 + lr;
            float bv = bc[col];
            f32x4 a = acc[rt][ct];
#pragma unroll
            for (int i = 0; i < 4; i++) {
                st[(lg * 4 + i) * SROW + col] = f2bf(a[i] + bv);
            }
        }
        __syncthreads();
        int rbase = base + rt * 16;
#pragma unroll
        for (int k = 0; k < 4; k++) {
            int ci = tid + k * 256;         // 0..1023
            int rl = ci >> 6;               // local row 0..15
            int cc = (ci & 63) * 8;         // col start (multiple of 8)
            int rg = rbase + rl;
            if (rg < N) {
                uint2 lo = *(const uint2*)&st[rl * SROW + cc];
                uint2 hi = *(const uint2*)&st[rl * SROW + cc + 4];
                uint4 val = make_uint4(lo.x, lo.y, hi.x, hi.y);
                if (cc < 256) *(uint4*)&xlb[(size_t)rg * HH + cc] = val;
                else          *(uint4*)&xrb[(size_t)rg * HH + (cc - 256)] = val;
            }
        }
        __syncthreads();
    }
}

// ---- K1: proj-L0 rows [0,25024) fused with degree histogram (independent) ----
__global__ __launch_bounds__(256) void k1_projhist_k(
    const float* __restrict__ x,
    const unsigned short* __restrict__ whi, const unsigned short* __restrict__ wlo,
    const float* __restrict__ bc,
    unsigned short* __restrict__ xlb, unsigned short* __restrict__ xrb,
    const int* __restrict__ dst, int* __restrict__ deg, int* __restrict__ rank)
{
    if (blockIdx.x < PH1) {
        proj_body<128>(blockIdx.x * 32, x, whi, wlo, bc, xlb, xrb);
    } else {
        int e = (blockIdx.x - PH1) * 256 + threadIdx.x;
        if (e < E) rank[e] = atomicAdd(&deg[dst[e]], 1);
    }
}

// ---- K2: proj-L0 rows [25024,N) fused with single-block full exclusive scan ----
// scan block (last): 256 threads x 196-elem chunks -> pre[] = full excl prefix of deg
__global__ __launch_bounds__(256) void k2_projscan_k(
    const float* __restrict__ x,
    const unsigned short* __restrict__ whi, const unsigned short* __restrict__ wlo,
    const float* __restrict__ bc,
    unsigned short* __restrict__ xlb, unsigned short* __restrict__ xrb,
    const int* __restrict__ deg, int* __restrict__ pre)
{
    if (blockIdx.x < PH2) {
        proj_body<128>(PH1_ROWS + blockIdx.x * 32, x, whi, wlo, bc, xlb, xrb);
    } else {
        constexpr int CH = 196; // 256*196 = 50176 >= N
        __shared__ int sums[256];
        int t = threadIdx.x;
        int cbase = t * CH;
        int cend = (cbase + CH < N) ? cbase + CH : N;
        int s = 0;
        for (int i = cbase; i < cend; ++i) s += deg[i];
        sums[t] = s;
        __syncthreads();
        for (int off = 1; off < 256; off <<= 1) {
            int tv = (t >= off) ? sums[t - off] : 0;
            __syncthreads();
            sums[t] += tv;
            __syncthreads();
        }
        int run = sums[t] - s;  // exclusive prefix of this chunk
        for (int i = cbase; i < cend; ++i) {
            pre[i] = run;
            run += deg[i];
        }
    }
}

// ---- scatter edges to CSR order (no atomics); compute eap on the fly ----
__global__ __launch_bounds__(256) void scatter_k(
    const int* __restrict__ src, const int* __restrict__ dst,
    const float* __restrict__ ea,
    const float* __restrict__ W_et, const float* __restrict__ b_et,
    const float* __restrict__ W_uw, const float* __restrict__ b_uw,
    const float* __restrict__ W_ua, const float* __restrict__ b_ua,
    const int* __restrict__ pre, const int* __restrict__ rank,
    int* __restrict__ csr_src, float* __restrict__ eap_csr)
{
    int e = blockIdx.x * 256 + threadIdx.x;
    if (e >= E) return;
    float et = ea[e * 2 + 0], uw = ea[e * 2 + 1];
    float ua = 1.f / (1.f + expf(-(uw * W_ua[0] + b_ua[0])));
    float4 v;
    v.x = et * W_et[0] + b_et[0];
    v.y = et * W_et[1] + b_et[1];
    v.z = (uw * W_uw[0] + b_uw[0]) * ua;
    v.w = (uw * W_uw[1] + b_uw[1]) * ua;
    int d = dst[e];
    int pos = pre[d] + rank[e];
    csr_src[pos] = src[e];
    *(float4*)&eap_csr[(size_t)pos * 4] = v;
}

// ---- standalone proj (layer 1) ----
template <int IC>
__global__ __launch_bounds__(256) void projmm_k(
    const float* __restrict__ x,
    const unsigned short* __restrict__ whi, const unsigned short* __restrict__ wlo,
    const float* __restrict__ bc,
    unsigned short* __restrict__ xlb, unsigned short* __restrict__ xrb)
{
    proj_body<IC>(blockIdx.x * 32, x, whi, wlo, bc, xlb, xrb);
}

// ---- fused GAT layer: persistent waves, static partition, shift-free softmax ----
// EXACT round-7 structure (verified 73.4us/layer, VGPR 56); pre[] is full prefix now.
__global__ __launch_bounds__(256) void gat_aggr_k(
    const unsigned short* __restrict__ xlb, const unsigned short* __restrict__ xrb,
    const float* __restrict__ eap_csr, const float* __restrict__ We,
    const float* __restrict__ att,
    const int* __restrict__ pre, const int* __restrict__ deg,
    const int* __restrict__ csr_src,
    const float* __restrict__ bias, float* __restrict__ hout)
{
    const int lane = threadIdx.x & 63;
    const int c4 = lane * 4;
    const float4 w0 = *(const float4*)&We[0 * HH + c4];
    const float4 w1 = *(const float4*)&We[1 * HH + c4];
    const float4 w2 = *(const float4*)&We[2 * HH + c4];
    const float4 w3 = *(const float4*)&We[3 * HH + c4];
    const float4 av = *(const float4*)&att[c4];
    float4 bb = make_float4(0.f, 0.f, 0.f, 0.f);
    if (lane < 16) bb = *(const float4*)&bias[c4];

    const int wid = __builtin_amdgcn_readfirstlane(blockIdx.x * 4 + (threadIdx.x >> 6));
    constexpr int q = N / GAT_WAVES;           // 6
    constexpr int r = N % GAT_WAVES;           // 836
    int d0 = wid * q + (wid < r ? wid : r);
    int dcnt = q + (wid < r ? 1 : 0);

    for (int d = d0; d < d0 + dcnt; ++d) {
        int start = pre[d];
        int end = start + deg[d];
        const float4 vr = ld_bf4(&xrb[(size_t)d * HH + c4]);
        float denom = 0.f;
        float ax = 0.f, ay = 0.f, az = 0.f, aw = 0.f;
        int idx = start;
        for (; idx + 4 <= end; idx += 4) {
            int s0 = csr_src[idx], s1 = csr_src[idx + 1];
            int s2 = csr_src[idx + 2], s3 = csr_src[idx + 3];
            float4 a0 = *(const float4*)&eap_csr[(size_t)(idx + 0) * 4];
            float4 a1 = *(const float4*)&eap_csr[(size_t)(idx + 1) * 4];
            float4 a2 = *(const float4*)&eap_csr[(size_t)(idx + 2) * 4];
            float4 a3 = *(const float4*)&eap_csr[(size_t)(idx + 3) * 4];
            float4 vl0 = ld_bf4(&xlb[(size_t)s0 * HH + c4]);
            float4 vl1 = ld_bf4(&xlb[(size_t)s1 * HH + c4]);
            float4 vl2 = ld_bf4(&xlb[(size_t)s2 * HH + c4]);
            float4 vl3 = ld_bf4(&xlb[(size_t)s3 * HH + c4]);
            float p0, p1, p2, p3;
            {
                float q0 = vl0.x + vr.x + a0.x * w0.x + a0.y * w1.x + a0.z * w2.x + a0.w * w3.x;
                float q1 = vl0.y + vr.y + a0.x * w0.y + a0.y * w1.y + a0.z * w2.y + a0.w * w3.y;
                float q2 = vl0.z + vr.z + a0.x * w0.z + a0.y * w1.z + a0.z * w2.z + a0.w * w3.z;
                float q3 = vl0.w + vr.w + a0.x * w0.w + a0.y * w1.w + a0.z * w2.w + a0.w * w3.w;
                q0 = fmaxf(q0, NEG * q0); q1 = fmaxf(q1, NEG * q1);
                q2 = fmaxf(q2, NEG * q2); q3 = fmaxf(q3, NEG * q3);
                p0 = q0 * av.x + q1 * av.y + q2 * av.z + q3 * av.w;
            }
            {
                float q0 = vl1.x + vr.x + a1.x * w0.x + a1.y * w1.x + a1.z * w2.x + a1.w * w3.x;
                float q1 = vl1.y + vr.y + a1.x * w0.y + a1.y * w1.y + a1.z * w2.y + a1.w * w3.y;
                float q2 = vl1.z + vr.z + a1.x * w0.z + a1.y * w1.z + a1.z * w2.z + a1.w * w3.z;
                float q3 = vl1.w + vr.w + a1.x * w0.w + a1.y * w1.w + a1.z * w2.w + a1.w * w3.w;
                q0 = fmaxf(q0, NEG * q0); q1 = fmaxf(q1, NEG * q1);
                q2 = fmaxf(q2, NEG * q2); q3 = fmaxf(q3, NEG * q3);
                p1 = q0 * av.x + q1 * av.y + q2 * av.z + q3 * av.w;
            }
            {
                float q0 = vl2.x + vr.x + a2.x * w0.x + a2.y * w1.x + a2.z * w2.x + a2.w * w3.x;
                float q1 = vl2.y + vr.y + a2.x * w0.y + a2.y * w1.y + a2.z * w2.y + a2.w * w3.y;
                float q2 = vl2.z + vr.z + a2.x * w0.z + a2.y * w1.z + a2.z * w2.z + a2.w * w3.z;
                float q3 = vl2.w + vr.w + a2.x * w0.w + a2.y * w1.w + a2.z * w2.w + a2.w * w3.w;
                q0 = fmaxf(q0, NEG * q0); q1 = fmaxf(q1, NEG * q1);
                q2 = fmaxf(q2, NEG * q2); q3 = fmaxf(q3, NEG * q3);
                p2 = q0 * av.x + q1 * av.y + q2 * av.z + q3 * av.w;
            }
            {
                float q0 = vl3.x + vr.x + a3.x * w0.x + a3.y * w1.x + a3.z * w2.x + a3.w * w3.x;
                float q1 = vl3.y + vr.y + a3.x * w0.y + a3.y * w1.y + a3.z * w2.y + a3.w * w3.y;
                float q2 = vl3.z + vr.z + a3.x * w0.z + a3.y * w1.z + a3.z * w2.z + a3.w * w3.z;
                float q3 = vl3.w + vr.w + a3.x * w0.w + a3.y * w1.w + a3.z * w2.w + a3.w * w3.w;
                q0 = fmaxf(q0, NEG * q0); q1 = fmaxf(q1, NEG * q1);
                q2 = fmaxf(q2, NEG * q2); q3 = fmaxf(q3, NEG * q3);
                p3 = q0 * av.x + q1 * av.y + q2 * av.z + q3 * av.w;
            }
#pragma unroll
            for (int off = 1; off <= 8; off <<= 1) {
                p0 += __shfl_xor(p0, off, 64);
                p1 += __shfl_xor(p1, off, 64);
                p2 += __shfl_xor(p2, off, 64);
                p3 += __shfl_xor(p3, off, 64);
            }
            float e0 = __expf(p0);
            float e1 = __expf(p1);
            float e2 = __expf(p2);
            float e3 = __expf(p3);
            denom += e0 + e1 + e2 + e3;
            ax += e0 * vl0.x + e1 * vl1.x + e2 * vl2.x + e3 * vl3.x;
            ay += e0 * vl0.y + e1 * vl1.y + e2 * vl2.y + e3 * vl3.y;
            az += e0 * vl0.z + e1 * vl1.z + e2 * vl2.z + e3 * vl3.z;
            aw += e0 * vl0.w + e1 * vl1.w + e2 * vl2.w + e3 * vl3.w;
        }
        for (; idx < end; ++idx) {
            int s = csr_src[idx];
            float4 a = *(const float4*)&eap_csr[(size_t)idx * 4];
            float4 vl = ld_bf4(&xlb[(size_t)s * HH + c4]);
            float q0 = vl.x + vr.x + a.x * w0.x + a.y * w1.x + a.z * w2.x + a.w * w3.x;
            float q1 = vl.y + vr.y + a.x * w0.y + a.y * w1.y + a.z * w2.y + a.w * w3.y;
            float q2 = vl.z + vr.z + a.x * w0.z + a.y * w1.z + a.z * w2.z + a.w * w3.z;
            float q3 = vl.w + vr.w + a.x * w0.w + a.y * w1.w + a.z * w2.w + a.w * w3.w;
            q0 = fmaxf(q0, NEG * q0); q1 = fmaxf(q1, NEG * q1);
            q2 = fmaxf(q2, NEG * q2); q3 = fmaxf(q3, NEG * q3);
            float p = q0 * av.x + q1 * av.y + q2 * av.z + q3 * av.w;
#pragma unroll
            for (int off = 1; off <= 8; off <<= 1) p += __shfl_xor(p, off, 64);
            float e = __expf(p);
            denom += e;
            ax += e * vl.x;
            ay += e * vl.y;
            az += e * vl.z;
            aw += e * vl.w;
        }
        float inv = 0.25f / (denom + 1e-16f);   // head-mean folded in
        ax *= inv; ay *= inv; az *= inv; aw *= inv;
        ax += __shfl_xor(ax, 16, 64); ax += __shfl_xor(ax, 32, 64);
        ay += __shfl_xor(ay, 16, 64); ay += __shfl_xor(ay, 32, 64);
        az += __shfl_xor(az, 16, 64); az += __shfl_xor(az, 32, 64);
        aw += __shfl_xor(aw, 16, 64); aw += __shfl_xor(aw, 32, 64);
        if (lane < 16) {
            float4 o;
            o.x = fmaxf(ax + bb.x, 0.f);
            o.y = fmaxf(ay + bb.y, 0.f);
            o.z = fmaxf(az + bb.z, 0.f);
            o.w = fmaxf(aw + bb.w, 0.f);
            *(float4*)&hout[(size_t)d * HID + c4] = o;
        }
    }
}

// ---- pooling: chunked segment sum (batch is sorted) ----
__global__ __launch_bounds__(256) void pool_k(
    const float* __restrict__ h, const int* __restrict__ batch,
    float* __restrict__ pooled)
{
    constexpr int CH = 16;
    int c = threadIdx.x & 63;
    int chunk = blockIdx.x * 4 + (threadIdx.x >> 6);
    int n0 = chunk * CH;
    if (n0 >= N) return;
    int nend = (n0 + CH < N) ? n0 + CH : N;
    float sum = 0.f;
    int curb = batch[n0];
    for (int n = n0; n < nend; ++n) {
        int b = batch[n];
        if (b != curb) {
            atomicAdd(&pooled[curb * HID + c], sum);
            sum = 0.f; curb = b;
        }
        sum += h[(size_t)n * HID + c];
    }
    atomicAdd(&pooled[curb * HID + c], sum);
}

// ---- MLP head: one block (64 threads) per graph ----
__global__ __launch_bounds__(64) void head_k(
    const float* __restrict__ pooled, const int* __restrict__ batch,
    const float* __restrict__ W_fc, const float* __restrict__ b_fc,
    const float* __restrict__ W_res, const float* __restrict__ b_res,
    const float* __restrict__ W_time, const float* __restrict__ b_time,
    float* __restrict__ out)
{
    int g = blockIdx.x;
    int c = threadIdx.x;
    int lo = 0, hi = N;
    while (lo < hi) { int mid = (lo + hi) >> 1; if (batch[mid] < g) lo = mid + 1; else hi = mid; }
    int start = lo;
    hi = N;
    while (lo < hi) { int mid = (lo + hi) >> 1; if (batch[mid] < g + 1) lo = mid + 1; else hi = mid; }
    int end = lo;
    float cnt = (float)(end - start);
    float p = pooled[g * HID + c] / fmaxf(cnt, 1.0f);
    __shared__ float ps[HID];
    ps[c] = p;
    __syncthreads();
    float gv = b_fc[c];
    for (int k = 0; k < HID; k++) gv += ps[k] * W_fc[k * HID + c];
    gv = fmaxf(gv, 0.f);
    float r = gv * W_res[c];
    float t = gv * W_time[c];
#pragma unroll
    for (int off = 32; off > 0; off >>= 1) {
        r += __shfl_down(r, off, 64);
        t += __shfl_down(t, off, 64);
    }
    if (c == 0) {
        out[g * 2 + 0] = r + b_res[0];
        out[g * 2 + 1] = t + b_time[0];
    }
}

} // namespace

extern "C" void kernel_launch(void* const* d_in, const int* in_sizes, int n_in,
                              void* d_out, int out_size, void* d_ws, size_t ws_size,
                              hipStream_t stream) {
    const float* x         = (const float*)d_in[0];
    const float* edge_attr = (const float*)d_in[1];
    const int*   edge_index= (const int*)d_in[2];
    const int*   batch     = (const int*)d_in[3];
    const float* W_et = (const float*)d_in[4];
    const float* b_et = (const float*)d_in[5];
    const float* W_uw = (const float*)d_in[6];
    const float* b_uw = (const float*)d_in[7];
    const float* W_ua = (const float*)d_in[8];
    const float* b_ua = (const float*)d_in[9];
    const float* Wl0  = (const float*)d_in[10];
    const float* bl0  = (const float*)d_in[11];
    const float* Wr0  = (const float*)d_in[12];
    const float* br0  = (const float*)d_in[13];
    const float* att0 = (const float*)d_in[14];
    const float* We0  = (const float*)d_in[15];
    const float* bias0= (const float*)d_in[16];
    const float* Wl1  = (const float*)d_in[17];
    const float* bl1  = (const float*)d_in[18];
    const float* Wr1  = (const float*)d_in[19];
    const float* br1  = (const float*)d_in[20];
    const float* att1 = (const float*)d_in[21];
    const float* We1  = (const float*)d_in[22];
    const float* bias1= (const float*)d_in[23];
    const float* W_fc = (const float*)d_in[24];
    const float* b_fc = (const float*)d_in[25];
    const float* W_res= (const float*)d_in[26];
    const float* b_res= (const float*)d_in[27];
    const float* W_time=(const float*)d_in[28];
    const float* b_time=(const float*)d_in[29];

    const int* src = edge_index;     // row 0
    const int* dst = edge_index + E; // row 1

    // workspace layout — same total footprint as the known-good kernel.
    // xl/xr fp32-sized regions: bf16 arrays in lower halves; xr upper half holds
    // the packed weights (written by prep_k, independent of the CSR chain).
    float* ws    = (float*)d_ws;
    unsigned short* xlb  = (unsigned short*)ws;                   // lower half of xl region
    float* xr_reg = ws + (size_t)N * HH;
    unsigned short* xrb  = (unsigned short*)xr_reg;               // lower half of xr region
    unsigned short* w0hi = (unsigned short*)xr_reg + (size_t)N * HH; // xr upper half
    unsigned short* w0lo = w0hi + 65536;
    unsigned short* w1hi = w0lo + 65536;
    unsigned short* w1lo = w1hi + 32768;
    float* bc0 = (float*)(w1lo + 32768);
    float* bc1 = bc0 + 512;
    float* h1    = ws  + (size_t)2 * N * HH;  // N*HID
    float* h2    = h1  + (size_t)N * HID;     // N*HID
    float* pooled= h2  + (size_t)N * HID;     // G*HID
    int*   deg      = (int*)(pooled + (size_t)G * HID); // N (adjacent to pooled)
    int*   pre      = deg + N;                // N (FULL exclusive prefix now)
    int*   bsum     = pre + N;                // 256 (unused; layout compat)
    int*   rank     = bsum + 256;             // E
    int*   csr_src  = rank + E;               // E
    float* eap_csr  = (float*)(csr_src + E);  // E*4

    dim3 b256(256);

    // 1. pack weights + zero pooled/deg (replaces memset dispatch)
    prep_k<<<PACK_BLOCKS + ZERO_BLOCKS, b256, 0, stream>>>(
        Wl0, Wr0, bl0, br0, Wl1, Wr1, bl1, br1,
        w0hi, w0lo, w1hi, w1lo, bc0, bc1, (int*)pooled);

    // 2. proj-L0 first half ∥ degree histogram (independent work, one launch)
    k1_projhist_k<<<PH1 + HIST_BLOCKS, b256, 0, stream>>>(
        x, w0hi, w0lo, bc0, xlb, xrb, dst, deg, rank);

    // 3. proj-L0 second half ∥ single-block full exclusive scan deg->pre
    k2_projscan_k<<<PH2 + 1, b256, 0, stream>>>(
        x, w0hi, w0lo, bc0, xlb, xrb, deg, pre);

    // 4. scatter edges to CSR order (rank-based, no atomics)
    scatter_k<<<HIST_BLOCKS, b256, 0, stream>>>(
        src, dst, edge_attr, W_et, b_et, W_uw, b_uw, W_ua, b_ua,
        pre, rank, csr_src, eap_csr);

    // 5. GAT layer 0
    gat_aggr_k<<<GAT_BLOCKS, b256, 0, stream>>>(
        xlb, xrb, eap_csr, We0, att0, pre, deg, csr_src, bias0, h1);

    // 6-7. layer 1
    projmm_k<64><<<NPROJ, b256, 0, stream>>>(h1, w1hi, w1lo, bc1, xlb, xrb);
    gat_aggr_k<<<GAT_BLOCKS, b256, 0, stream>>>(
        xlb, xrb, eap_csr, We1, att1, pre, deg, csr_src, bias1, h2);

    // 8-9. pooling + head
    pool_k<<<((N + 15) / 16 + 3) / 4, b256, 0, stream>>>(h2, batch, pooled);
    head_k<<<G, dim3(64), 0, stream>>>(
        pooled, batch, W_fc, b_fc, W_res, b_res, W_time, b_time, (float*)d_out);
}

// Round 11
// 366.423 us; speedup vs baseline: 1.2013x; 1.2013x over previous
//
#include <hip/hip_runtime.h>
#include <math.h>

namespace {

constexpr int N = 50000;
constexpr int E = 400000;
constexpr int G = 64;
constexpr int HID = 64;
constexpr int HH = 256; // NHEAD*HID
constexpr int NCT = 32; // 512 output cols (xl|xr) / 16
constexpr float NEG = 0.2f;
constexpr int GAT_BLOCKS = 2048; // 8 blocks/CU * 256 CU
constexpr int GAT_WAVES = GAT_BLOCKS * 4;

constexpr int NPROJ = (N + 31) / 32;         // 1563
constexpr int PH1 = 782;                     // proj-L0 first-half blocks
constexpr int PH1_ROWS = PH1 * 32;           // 25024
constexpr int PH2 = NPROJ - PH1;             // 781
constexpr int HIST_BLOCKS = (E + 255) / 256; // 1563
constexpr int NB = (N + 255) / 256;          // 196 (scan1 blocks)
constexpr int PACK_BLOCKS = 52;              // weight-pack threads
constexpr int ZERO_ELEMS = G * HID + N;      // pooled + deg (adjacent)
constexpr int ZERO_BLOCKS = (ZERO_ELEMS + 255) / 256;

typedef __attribute__((ext_vector_type(8))) short short8v;
typedef __attribute__((ext_vector_type(4))) float f32x4;

__device__ __forceinline__ unsigned short f2bf(float f) {
    unsigned int u = __float_as_uint(f);
    u += 0x7FFFu + ((u >> 16) & 1u); // RTNE
    return (unsigned short)(u >> 16);
}
__device__ __forceinline__ float bf2f(unsigned short h) {
    return __uint_as_float(((unsigned int)h) << 16);
}
// load 4 consecutive bf16 (8B aligned) -> float4
__device__ __forceinline__ float4 ld_bf4(const unsigned short* p) {
    uint2 u = *(const uint2*)p;
    float4 r;
    r.x = __uint_as_float(u.x << 16);
    r.y = __uint_as_float(u.x & 0xFFFF0000u);
    r.z = __uint_as_float(u.y << 16);
    r.w = __uint_as_float(u.y & 0xFFFF0000u);
    return r;
}

// ---- prep: pack W into MFMA B-fragment order (hi/lo bf16) + zero pooled/deg ----
__global__ __launch_bounds__(256) void prep_k(
    const float* __restrict__ Wl0, const float* __restrict__ Wr0,
    const float* __restrict__ bl0, const float* __restrict__ br0,
    const float* __restrict__ Wl1, const float* __restrict__ Wr1,
    const float* __restrict__ bl1, const float* __restrict__ br1,
    unsigned short* __restrict__ w0hi, unsigned short* __restrict__ w0lo,
    unsigned short* __restrict__ w1hi, unsigned short* __restrict__ w1lo,
    float* __restrict__ bc0, float* __restrict__ bc1,
    int* __restrict__ zero_base)
{
    int b = blockIdx.x;
    if (b >= PACK_BLOCKS) {
        int i = (b - PACK_BLOCKS) * 256 + threadIdx.x;
        if (i < ZERO_ELEMS) zero_base[i] = 0;
        return;
    }
    int idx = b * 256 + threadIdx.x;
    if (idx < 8192) { // layer0: KT=4, 4*32*64 slots
        int lane = idx & 63, ct = (idx >> 6) & 31, kt = idx >> 11;
        int col = ct * 16 + (lane & 15);
        const float* W = (col < 256) ? Wl0 : Wr0;
        int c = col & 255;
        int kb = kt * 32 + ((lane >> 4) & 3) * 8;
#pragma unroll
        for (int e = 0; e < 8; e++) {
            float v = W[(size_t)(kb + e) * 256 + c];
            unsigned short hi = f2bf(v);
            unsigned short lo = f2bf(v - bf2f(hi));
            w0hi[(size_t)idx * 8 + e] = hi;
            w0lo[(size_t)idx * 8 + e] = lo;
        }
    } else if (idx < 8192 + 4096) { // layer1: KT=2
        int s = idx - 8192;
        int lane = s & 63, ct = (s >> 6) & 31, kt = s >> 11;
        int col = ct * 16 + (lane & 15);
        const float* W = (col < 256) ? Wl1 : Wr1;
        int c = col & 255;
        int kb = kt * 32 + ((lane >> 4) & 3) * 8;
#pragma unroll
        for (int e = 0; e < 8; e++) {
            float v = W[(size_t)(kb + e) * 256 + c];
            unsigned short hi = f2bf(v);
            unsigned short lo = f2bf(v - bf2f(hi));
            w1hi[(size_t)s * 8 + e] = hi;
            w1lo[(size_t)s * 8 + e] = lo;
        }
    } else if (idx < 8192 + 4096 + 512) {
        int i = idx - (8192 + 4096);
        bc0[i] = (i < 256) ? bl0[i] : br0[i - 256];
    } else if (idx < 8192 + 4096 + 1024) {
        int i = idx - (8192 + 4096 + 512);
        bc1[i] = (i < 256) ? bl1[i] : br1[i - 256];
    }
}

// ---- node projection body (round-7 verified form), parameterized by row base ----
template <int IC>
__device__ __forceinline__ void proj_body(
    int base,
    const float* __restrict__ x,
    const unsigned short* __restrict__ whi, const unsigned short* __restrict__ wlo,
    const float* __restrict__ bc,
    unsigned short* __restrict__ xlb, unsigned short* __restrict__ xrb)
{
    constexpr int KT = IC / 32;
    constexpr int LDX = IC + 4;
    constexpr int SROW = 516;
    constexpr int XS_BYTES = 32 * LDX * 4;
    constexpr int ST_BYTES = 16 * SROW * 2;
    constexpr int SMEM_BYTES = (XS_BYTES > ST_BYTES) ? XS_BYTES : ST_BYTES;
    __shared__ char smem[SMEM_BYTES];
    float (*xs)[LDX] = (float (*)[LDX])smem;
    const int tid = threadIdx.x;
    for (int idx = tid; idx < 32 * IC / 4; idx += 256) {
        int j = idx / (IC / 4), k4 = idx - j * (IC / 4);
        int n = base + j;
        float4 v = make_float4(0.f, 0.f, 0.f, 0.f);
        if (n < N) v = *(const float4*)&x[(size_t)n * IC + k4 * 4];
        *(float4*)&xs[j][k4 * 4] = v;
    }
    __syncthreads();
    const int w = tid >> 6, lane = tid & 63;
    const int lr = lane & 15, lg = lane >> 4;
    f32x4 acc[2][8];
#pragma unroll
    for (int rt = 0; rt < 2; rt++)
#pragma unroll
        for (int ct = 0; ct < 8; ct++) {
            f32x4 z = {0.f, 0.f, 0.f, 0.f};
            acc[rt][ct] = z;
        }
#pragma unroll
    for (int kt = 0; kt < KT; kt++) {
        short8v ahi[2], alo[2];
#pragma unroll
        for (int rt = 0; rt < 2; rt++) {
            const float* p = &xs[rt * 16 + lr][kt * 32 + lg * 8];
            float4 v0 = *(const float4*)p;
            float4 v1 = *(const float4*)(p + 4);
            float fv[8] = {v0.x, v0.y, v0.z, v0.w, v1.x, v1.y, v1.z, v1.w};
            short8v h, l;
#pragma unroll
            for (int e = 0; e < 8; e++) {
                unsigned short hb = f2bf(fv[e]);
                h[e] = (short)hb;
                l[e] = (short)f2bf(fv[e] - bf2f(hb));
            }
            ahi[rt] = h;
            alo[rt] = l;
        }
        const size_t bbase = ((size_t)(kt * NCT + w * 8) * 64 + lane) * 8;
#pragma unroll
        for (int ct = 0; ct < 8; ct++) {
            short8v bhi = *(const short8v*)&whi[bbase + (size_t)ct * 64 * 8];
            short8v blo = *(const short8v*)&wlo[bbase + (size_t)ct * 64 * 8];
#pragma unroll
            for (int rt = 0; rt < 2; rt++) {
                acc[rt][ct] = __builtin_amdgcn_mfma_f32_16x16x32_bf16(ahi[rt], bhi, acc[rt][ct], 0, 0, 0);
                acc[rt][ct] = __builtin_amdgcn_mfma_f32_16x16x32_bf16(alo[rt], bhi, acc[rt][ct], 0, 0, 0);
                acc[rt][ct] = __builtin_amdgcn_mfma_f32_16x16x32_bf16(ahi[rt], blo, acc[rt][ct], 0, 0, 0);
            }
        }
    }
    // epilogue: C/D layout (measured): col = lane&15, row = (lane>>4)*4 + reg
    __syncthreads();
    unsigned short* st = (unsigned short*)smem;
#pragma unroll
    for (int rt = 0; rt < 2; rt++) {
#pragma unroll
        for (int ct = 0; ct < 8; ct++) {
            int col = (w * 8 + ct) * 16 + lr;
            float bv = bc[col];
            f32x4 a = acc[rt][ct];
#pragma unroll
            for (int i = 0; i < 4; i++) {
                st[(lg * 4 + i) * SROW + col] = f2bf(a[i] + bv);
            }
        }
        __syncthreads();
        int rbase = base + rt * 16;
#pragma unroll
        for (int k = 0; k < 4; k++) {
            int ci = tid + k * 256;
            int rl = ci >> 6;
            int cc = (ci & 63) * 8;
            int rg = rbase + rl;
            if (rg < N) {
                uint2 lo = *(const uint2*)&st[rl * SROW + cc];
                uint2 hi = *(const uint2*)&st[rl * SROW + cc + 4];
                uint4 val = make_uint4(lo.x, lo.y, hi.x, hi.y);
                if (cc < 256) *(uint4*)&xlb[(size_t)rg * HH + cc] = val;
                else          *(uint4*)&xrb[(size_t)rg * HH + (cc - 256)] = val;
            }
        }
        __syncthreads();
    }
}

// ---- K1: proj-L0 first half ∥ degree histogram (independent work) ----
__global__ __launch_bounds__(256) void k1_projhist_k(
    const float* __restrict__ x,
    const unsigned short* __restrict__ whi, const unsigned short* __restrict__ wlo,
    const float* __restrict__ bc,
    unsigned short* __restrict__ xlb, unsigned short* __restrict__ xrb,
    const int* __restrict__ dst, int* __restrict__ deg, int* __restrict__ rank)
{
    if (blockIdx.x < PH1) {
        proj_body<128>(blockIdx.x * 32, x, whi, wlo, bc, xlb, xrb);
    } else {
        int e = (blockIdx.x - PH1) * 256 + threadIdx.x;
        if (e < E) rank[e] = atomicAdd(&deg[dst[e]], 1);
    }
}

// ---- K2: proj-L0 second half ∥ PARALLEL scan1 (196 blocks, round-7 form) ----
__global__ __launch_bounds__(256) void k2_projscan1_k(
    const float* __restrict__ x,
    const unsigned short* __restrict__ whi, const unsigned short* __restrict__ wlo,
    const float* __restrict__ bc,
    unsigned short* __restrict__ xlb, unsigned short* __restrict__ xrb,
    const int* __restrict__ deg, int* __restrict__ pre, int* __restrict__ bsum)
{
    if (blockIdx.x < PH2) {
        proj_body<128>(PH1_ROWS + blockIdx.x * 32, x, whi, wlo, bc, xlb, xrb);
    } else {
        __shared__ int s[256];
        int sb = blockIdx.x - PH2;
        int i = sb * 256 + threadIdx.x;
        int v = (i < N) ? deg[i] : 0;
        s[threadIdx.x] = v;
        __syncthreads();
        for (int off = 1; off < 256; off <<= 1) {
            int t = (threadIdx.x >= off) ? s[threadIdx.x - off] : 0;
            __syncthreads();
            s[threadIdx.x] += t;
            __syncthreads();
        }
        if (i < N) pre[i] = s[threadIdx.x] - v;
        if (threadIdx.x == 255) bsum[sb] = s[255];
    }
}

// ---- scan2: exclusive prefix over block totals (1 tiny block) ----
__global__ __launch_bounds__(256) void scan2_k(int* __restrict__ bsum, int nb)
{
    __shared__ int s[256];
    int tid = threadIdx.x;
    int v = (tid < nb) ? bsum[tid] : 0;
    s[tid] = v;
    __syncthreads();
    for (int off = 1; off < 256; off <<= 1) {
        int t = (tid >= off) ? s[tid - off] : 0;
        __syncthreads();
        s[tid] += t;
        __syncthreads();
    }
    if (tid < nb) bsum[tid] = s[tid] - v;
}

// ---- scatter edges to CSR order (no atomics); compute eap on the fly ----
__global__ __launch_bounds__(256) void scatter_k(
    const int* __restrict__ src, const int* __restrict__ dst,
    const float* __restrict__ ea,
    const float* __restrict__ W_et, const float* __restrict__ b_et,
    const float* __restrict__ W_uw, const float* __restrict__ b_uw,
    const float* __restrict__ W_ua, const float* __restrict__ b_ua,
    const int* __restrict__ pre, const int* __restrict__ bsum,
    const int* __restrict__ rank,
    int* __restrict__ csr_src, float* __restrict__ eap_csr)
{
    int e = blockIdx.x * 256 + threadIdx.x;
    if (e >= E) return;
    float et = ea[e * 2 + 0], uw = ea[e * 2 + 1];
    float ua = 1.f / (1.f + expf(-(uw * W_ua[0] + b_ua[0])));
    float4 v;
    v.x = et * W_et[0] + b_et[0];
    v.y = et * W_et[1] + b_et[1];
    v.z = (uw * W_uw[0] + b_uw[0]) * ua;
    v.w = (uw * W_uw[1] + b_uw[1]) * ua;
    int d = dst[e];
    int pos = pre[d] + bsum[d >> 8] + rank[e];
    csr_src[pos] = src[e];
    *(float4*)&eap_csr[(size_t)pos * 4] = v;
}

// ---- standalone proj (layer 1) ----
template <int IC>
__global__ __launch_bounds__(256) void projmm_k(
    const float* __restrict__ x,
    const unsigned short* __restrict__ whi, const unsigned short* __restrict__ wlo,
    const float* __restrict__ bc,
    unsigned short* __restrict__ xlb, unsigned short* __restrict__ xrb)
{
    proj_body<IC>(blockIdx.x * 32, x, whi, wlo, bc, xlb, xrb);
}

// ---- fused GAT layer: EXACT round-7 structure (verified 73.4us/layer, VGPR 56) ----
__global__ __launch_bounds__(256) void gat_aggr_k(
    const unsigned short* __restrict__ xlb, const unsigned short* __restrict__ xrb,
    const float* __restrict__ eap_csr, const float* __restrict__ We,
    const float* __restrict__ att,
    const int* __restrict__ pre, const int* __restrict__ bsum,
    const int* __restrict__ deg,
    const int* __restrict__ csr_src,
    const float* __restrict__ bias, float* __restrict__ hout)
{
    const int lane = threadIdx.x & 63;
    const int c4 = lane * 4;
    const float4 w0 = *(const float4*)&We[0 * HH + c4];
    const float4 w1 = *(const float4*)&We[1 * HH + c4];
    const float4 w2 = *(const float4*)&We[2 * HH + c4];
    const float4 w3 = *(const float4*)&We[3 * HH + c4];
    const float4 av = *(const float4*)&att[c4];
    float4 bb = make_float4(0.f, 0.f, 0.f, 0.f);
    if (lane < 16) bb = *(const float4*)&bias[c4];

    const int wid = __builtin_amdgcn_readfirstlane(blockIdx.x * 4 + (threadIdx.x >> 6));
    constexpr int q = N / GAT_WAVES;           // 6
    constexpr int r = N % GAT_WAVES;           // 836
    int d0 = wid * q + (wid < r ? wid : r);
    int dcnt = q + (wid < r ? 1 : 0);

    for (int d = d0; d < d0 + dcnt; ++d) {
        int start = pre[d] + bsum[d >> 8];
        int end = start + deg[d];
        const float4 vr = ld_bf4(&xrb[(size_t)d * HH + c4]);
        float denom = 0.f;
        float ax = 0.f, ay = 0.f, az = 0.f, aw = 0.f;
        int idx = start;
        for (; idx + 4 <= end; idx += 4) {
            int s0 = csr_src[idx], s1 = csr_src[idx + 1];
            int s2 = csr_src[idx + 2], s3 = csr_src[idx + 3];
            float4 a0 = *(const float4*)&eap_csr[(size_t)(idx + 0) * 4];
            float4 a1 = *(const float4*)&eap_csr[(size_t)(idx + 1) * 4];
            float4 a2 = *(const float4*)&eap_csr[(size_t)(idx + 2) * 4];
            float4 a3 = *(const float4*)&eap_csr[(size_t)(idx + 3) * 4];
            float4 vl0 = ld_bf4(&xlb[(size_t)s0 * HH + c4]);
            float4 vl1 = ld_bf4(&xlb[(size_t)s1 * HH + c4]);
            float4 vl2 = ld_bf4(&xlb[(size_t)s2 * HH + c4]);
            float4 vl3 = ld_bf4(&xlb[(size_t)s3 * HH + c4]);
            float p0, p1, p2, p3;
            {
                float q0 = vl0.x + vr.x + a0.x * w0.x + a0.y * w1.x + a0.z * w2.x + a0.w * w3.x;
                float q1 = vl0.y + vr.y + a0.x * w0.y + a0.y * w1.y + a0.z * w2.y + a0.w * w3.y;
                float q2 = vl0.z + vr.z + a0.x * w0.z + a0.y * w1.z + a0.z * w2.z + a0.w * w3.z;
                float q3 = vl0.w + vr.w + a0.x * w0.w + a0.y * w1.w + a0.z * w2.w + a0.w * w3.w;
                q0 = fmaxf(q0, NEG * q0); q1 = fmaxf(q1, NEG * q1);
                q2 = fmaxf(q2, NEG * q2); q3 = fmaxf(q3, NEG * q3);
                p0 = q0 * av.x + q1 * av.y + q2 * av.z + q3 * av.w;
            }
            {
                float q0 = vl1.x + vr.x + a1.x * w0.x + a1.y * w1.x + a1.z * w2.x + a1.w * w3.x;
                float q1 = vl1.y + vr.y + a1.x * w0.y + a1.y * w1.y + a1.z * w2.y + a1.w * w3.y;
                float q2 = vl1.z + vr.z + a1.x * w0.z + a1.y * w1.z + a1.z * w2.z + a1.w * w3.z;
                float q3 = vl1.w + vr.w + a1.x * w0.w + a1.y * w1.w + a1.z * w2.w + a1.w * w3.w;
                q0 = fmaxf(q0, NEG * q0); q1 = fmaxf(q1, NEG * q1);
                q2 = fmaxf(q2, NEG * q2); q3 = fmaxf(q3, NEG * q3);
                p1 = q0 * av.x + q1 * av.y + q2 * av.z + q3 * av.w;
            }
            {
                float q0 = vl2.x + vr.x + a2.x * w0.x + a2.y * w1.x + a2.z * w2.x + a2.w * w3.x;
                float q1 = vl2.y + vr.y + a2.x * w0.y + a2.y * w1.y + a2.z * w2.y + a2.w * w3.y;
                float q2 = vl2.z + vr.z + a2.x * w0.z + a2.y * w1.z + a2.z * w2.z + a2.w * w3.z;
                float q3 = vl2.w + vr.w + a2.x * w0.w + a2.y * w1.w + a2.z * w2.w + a2.w * w3.w;
                q0 = fmaxf(q0, NEG * q0); q1 = fmaxf(q1, NEG * q1);
                q2 = fmaxf(q2, NEG * q2); q3 = fmaxf(q3, NEG * q3);
                p2 = q0 * av.x + q1 * av.y + q2 * av.z + q3 * av.w;
            }
            {
                float q0 = vl3.x + vr.x + a3.x * w0.x + a3.y * w1.x + a3.z * w2.x + a3.w * w3.x;
                float q1 = vl3.y + vr.y + a3.x * w0.y + a3.y * w1.y + a3.z * w2.y + a3.w * w3.y;
                float q2 = vl3.z + vr.z + a3.x * w0.z + a3.y * w1.z + a3.z * w2.z + a3.w * w3.z;
                float q3 = vl3.w + vr.w + a3.x * w0.w + a3.y * w1.w + a3.z * w2.w + a3.w * w3.w;
                q0 = fmaxf(q0, NEG * q0); q1 = fmaxf(q1, NEG * q1);
                q2 = fmaxf(q2, NEG * q2); q3 = fmaxf(q3, NEG * q3);
                p3 = q0 * av.x + q1 * av.y + q2 * av.z + q3 * av.w;
            }
#pragma unroll
            for (int off = 1; off <= 8; off <<= 1) {
                p0 += __shfl_xor(p0, off, 64);
                p1 += __shfl_xor(p1, off, 64);
                p2 += __shfl_xor(p2, off, 64);
                p3 += __shfl_xor(p3, off, 64);
            }
            float e0 = __expf(p0);
            float e1 = __expf(p1);
            float e2 = __expf(p2);
            float e3 = __expf(p3);
            denom += e0 + e1 + e2 + e3;
            ax += e0 * vl0.x + e1 * vl1.x + e2 * vl2.x + e3 * vl3.x;
            ay += e0 * vl0.y + e1 * vl1.y + e2 * vl2.y + e3 * vl3.y;
            az += e0 * vl0.z + e1 * vl1.z + e2 * vl2.z + e3 * vl3.z;
            aw += e0 * vl0.w + e1 * vl1.w + e2 * vl2.w + e3 * vl3.w;
        }
        for (; idx < end; ++idx) {
            int s = csr_src[idx];
            float4 a = *(const float4*)&eap_csr[(size_t)idx * 4];
            float4 vl = ld_bf4(&xlb[(size_t)s * HH + c4]);
            float q0 = vl.x + vr.x + a.x * w0.x + a.y * w1.x + a.z * w2.x + a.w * w3.x;
            float q1 = vl.y + vr.y + a.x * w0.y + a.y * w1.y + a.z * w2.y + a.w * w3.y;
            float q2 = vl.z + vr.z + a.x * w0.z + a.y * w1.z + a.z * w2.z + a.w * w3.z;
            float q3 = vl.w + vr.w + a.x * w0.w + a.y * w1.w + a.z * w2.w + a.w * w3.w;
            q0 = fmaxf(q0, NEG * q0); q1 = fmaxf(q1, NEG * q1);
            q2 = fmaxf(q2, NEG * q2); q3 = fmaxf(q3, NEG * q3);
            float p = q0 * av.x + q1 * av.y + q2 * av.z + q3 * av.w;
#pragma unroll
            for (int off = 1; off <= 8; off <<= 1) p += __shfl_xor(p, off, 64);
            float e = __expf(p);
            denom += e;
            ax += e * vl.x;
            ay += e * vl.y;
            az += e * vl.z;
            aw += e * vl.w;
        }
        float inv = 0.25f / (denom + 1e-16f);   // head-mean folded in
        ax *= inv; ay *= inv; az *= inv; aw *= inv;
        ax += __shfl_xor(ax, 16, 64); ax += __shfl_xor(ax, 32, 64);
        ay += __shfl_xor(ay, 16, 64); ay += __shfl_xor(ay, 32, 64);
        az += __shfl_xor(az, 16, 64); az += __shfl_xor(az, 32, 64);
        aw += __shfl_xor(aw, 16, 64); aw += __shfl_xor(aw, 32, 64);
        if (lane < 16) {
            float4 o;
            o.x = fmaxf(ax + bb.x, 0.f);
            o.y = fmaxf(ay + bb.y, 0.f);
            o.z = fmaxf(az + bb.z, 0.f);
            o.w = fmaxf(aw + bb.w, 0.f);
            *(float4*)&hout[(size_t)d * HID + c4] = o;
        }
    }
}

// ---- pooling: chunked segment sum (batch is sorted) ----
__global__ __launch_bounds__(256) void pool_k(
    const float* __restrict__ h, const int* __restrict__ batch,
    float* __restrict__ pooled)
{
    constexpr int CH = 16;
    int c = threadIdx.x & 63;
    int chunk = blockIdx.x * 4 + (threadIdx.x >> 6);
    int n0 = chunk * CH;
    if (n0 >= N) return;
    int nend = (n0 + CH < N) ? n0 + CH : N;
    float sum = 0.f;
    int curb = batch[n0];
    for (int n = n0; n < nend; ++n) {
        int b = batch[n];
        if (b != curb) {
            atomicAdd(&pooled[curb * HID + c], sum);
            sum = 0.f; curb = b;
        }
        sum += h[(size_t)n * HID + c];
    }
    atomicAdd(&pooled[curb * HID + c], sum);
}

// ---- MLP head: one block (64 threads) per graph ----
__global__ __launch_bounds__(64) void head_k(
    const float* __restrict__ pooled, const int* __restrict__ batch,
    const float* __restrict__ W_fc, const float* __restrict__ b_fc,
    const float* __restrict__ W_res, const float* __restrict__ b_res,
    const float* __restrict__ W_time, const float* __restrict__ b_time,
    float* __restrict__ out)
{
    int g = blockIdx.x;
    int c = threadIdx.x;
    int lo = 0, hi = N;
    while (lo < hi) { int mid = (lo + hi) >> 1; if (batch[mid] < g) lo = mid + 1; else hi = mid; }
    int start = lo;
    hi = N;
    while (lo < hi) { int mid = (lo + hi) >> 1; if (batch[mid] < g + 1) lo = mid + 1; else hi = mid; }
    int end = lo;
    float cnt = (float)(end - start);
    float p = pooled[g * HID + c] / fmaxf(cnt, 1.0f);
    __shared__ float ps[HID];
    ps[c] = p;
    __syncthreads();
    float gv = b_fc[c];
    for (int k = 0; k < HID; k++) gv += ps[k] * W_fc[k * HID + c];
    gv = fmaxf(gv, 0.f);
    float r = gv * W_res[c];
    float t = gv * W_time[c];
#pragma unroll
    for (int off = 32; off > 0; off >>= 1) {
        r += __shfl_down(r, off, 64);
        t += __shfl_down(t, off, 64);
    }
    if (c == 0) {
        out[g * 2 + 0] = r + b_res[0];
        out[g * 2 + 1] = t + b_time[0];
    }
}

} // namespace

extern "C" void kernel_launch(void* const* d_in, const int* in_sizes, int n_in,
                              void* d_out, int out_size, void* d_ws, size_t ws_size,
                              hipStream_t stream) {
    const float* x         = (const float*)d_in[0];
    const float* edge_attr = (const float*)d_in[1];
    const int*   edge_index= (const int*)d_in[2];
    const int*   batch     = (const int*)d_in[3];
    const float* W_et = (const float*)d_in[4];
    const float* b_et = (const float*)d_in[5];
    const float* W_uw = (const float*)d_in[6];
    const float* b_uw = (const float*)d_in[7];
    const float* W_ua = (const float*)d_in[8];
    const float* b_ua = (const float*)d_in[9];
    const float* Wl0  = (const float*)d_in[10];
    const float* bl0  = (const float*)d_in[11];
    const float* Wr0  = (const float*)d_in[12];
    const float* br0  = (const float*)d_in[13];
    const float* att0 = (const float*)d_in[14];
    const float* We0  = (const float*)d_in[15];
    const float* bias0= (const float*)d_in[16];
    const float* Wl1  = (const float*)d_in[17];
    const float* bl1  = (const float*)d_in[18];
    const float* Wr1  = (const float*)d_in[19];
    const float* br1  = (const float*)d_in[20];
    const float* att1 = (const float*)d_in[21];
    const float* We1  = (const float*)d_in[22];
    const float* bias1= (const float*)d_in[23];
    const float* W_fc = (const float*)d_in[24];
    const float* b_fc = (const float*)d_in[25];
    const float* W_res= (const float*)d_in[26];
    const float* b_res= (const float*)d_in[27];
    const float* W_time=(const float*)d_in[28];
    const float* b_time=(const float*)d_in[29];

    const int* src = edge_index;     // row 0
    const int* dst = edge_index + E; // row 1

    // workspace layout — same total footprint as the known-good kernel.
    float* ws    = (float*)d_ws;
    unsigned short* xlb  = (unsigned short*)ws;                   // lower half of xl region
    float* xr_reg = ws + (size_t)N * HH;
    unsigned short* xrb  = (unsigned short*)xr_reg;               // lower half of xr region
    unsigned short* w0hi = (unsigned short*)xr_reg + (size_t)N * HH; // xr upper half
    unsigned short* w0lo = w0hi + 65536;
    unsigned short* w1hi = w0lo + 65536;
    unsigned short* w1lo = w1hi + 32768;
    float* bc0 = (float*)(w1lo + 32768);
    float* bc1 = bc0 + 512;
    float* h1    = ws  + (size_t)2 * N * HH;  // N*HID
    float* h2    = h1  + (size_t)N * HID;     // N*HID
    float* pooled= h2  + (size_t)N * HID;     // G*HID
    int*   deg      = (int*)(pooled + (size_t)G * HID); // N (adjacent to pooled)
    int*   pre      = deg + N;                // N (block-local exclusive prefix)
    int*   bsum     = pre + N;                // 256 (block totals -> excl prefix)
    int*   rank     = bsum + 256;             // E
    int*   csr_src  = rank + E;               // E
    float* eap_csr  = (float*)(csr_src + E);  // E*4

    dim3 b256(256);

    // 1. pack weights + zero pooled/deg (replaces memset dispatch)
    prep_k<<<PACK_BLOCKS + ZERO_BLOCKS, b256, 0, stream>>>(
        Wl0, Wr0, bl0, br0, Wl1, Wr1, bl1, br1,
        w0hi, w0lo, w1hi, w1lo, bc0, bc1, (int*)pooled);

    // 2. proj-L0 first half ∥ degree histogram
    k1_projhist_k<<<PH1 + HIST_BLOCKS, b256, 0, stream>>>(
        x, w0hi, w0lo, bc0, xlb, xrb, dst, deg, rank);

    // 3. proj-L0 second half ∥ parallel scan1 (196 blocks)
    k2_projscan1_k<<<PH2 + NB, b256, 0, stream>>>(
        x, w0hi, w0lo, bc0, xlb, xrb, deg, pre, bsum);

    // 4. scan2 (tiny) + scatter
    scan2_k<<<1, b256, 0, stream>>>(bsum, NB);
    scatter_k<<<HIST_BLOCKS, b256, 0, stream>>>(
        src, dst, edge_attr, W_et, b_et, W_uw, b_uw, W_ua, b_ua,
        pre, bsum, rank, csr_src, eap_csr);

    // 5. GAT layer 0
    gat_aggr_k<<<GAT_BLOCKS, b256, 0, stream>>>(
        xlb, xrb, eap_csr, We0, att0, pre, bsum, deg, csr_src, bias0, h1);

    // 6-7. layer 1
    projmm_k<64><<<NPROJ, b256, 0, stream>>>(h1, w1hi, w1lo, bc1, xlb, xrb);
    gat_aggr_k<<<GAT_BLOCKS, b256, 0, stream>>>(
        xlb, xrb, eap_csr, We1, att1, pre, bsum, deg, csr_src, bias1, h2);

    // 8-9. pooling + head
    pool_k<<<((N + 15) / 16 + 3) / 4, b256, 0, stream>>>(h2, batch, pooled);
    head_k<<<G, dim3(64), 0, stream>>>(
        pooled, batch, W_fc, b_fc, W_res, b_res, W_time, b_time, (float*)d_out);
}